// Round 11
// baseline (142.008 us; speedup 1.0000x reference)
//
#include <hip/hip_runtime.h>
#include <cmath>

#define NB   2048
#define ND   512
#define NL   8
#define NLAB 128
#define MAXM 64
#define TOPK_ 5
#define NTH  256
#define MAXSLOT 9            // ceil(64*65/2 / 256)
#define MAXST   8            // ceil(64*32 / 256) staging float4 per thread
#define GSTRIDE (MAXM*MAXM)  // 4096 floats per (label,layer) gram

// ---------------------------------------------------------------------------
// Fused bucket + raw Gram per (label, layer). Round-11: register-prefetch
// software pipeline (next chunk's global loads issued before compute) and
// wave-shuffle bucket scan (16 barriers -> 1). Layer-7 blocks also run
// phase-1 (full-group knn -> insub) from their in-LDS tile.
// ---------------------------------------------------------------------------
__global__ __launch_bounds__(NTH) void k_gram(
    const float* __restrict__ feats, const int* __restrict__ labels,
    float* __restrict__ G, int* __restrict__ cnt,
    unsigned long long* __restrict__ insub)
{
    __shared__ int wsum[4];
    __shared__ int g_s[MAXM];
    __shared__ float Xt[MAXM][132];   // 132%4==0 -> aligned float4 rows; reused as 64x65 tile
    __shared__ float rinvp[64];
    __shared__ unsigned long long tops_s[64];
    __shared__ unsigned char keep_s[64];
    int c = blockIdx.x, l = blockIdx.y, tid = threadIdx.x;
    int lane = tid & 63, wv = tid >> 6;

    // ---- bucket via wave scan (deterministic, index-ascending) ----
    int my[8]; int n = 0; int base_i = tid * 8;
    for (int t = 0; t < 8; ++t) {
        int i = base_i + t;
        if (labels[i] == c) my[n++] = i;
    }
    int scan = n;
    #pragma unroll
    for (int off = 1; off < 64; off <<= 1) {
        int v = __shfl_up(scan, off);
        if (lane >= off) scan += v;
    }
    if (lane == 63) wsum[wv] = scan;
    __syncthreads();
    int w0 = wsum[0], w1 = wsum[1], w2 = wsum[2], w3 = wsum[3];
    int m = w0 + w1 + w2 + w3; if (m > MAXM) m = MAXM;
    int base = (wv > 0 ? w0 : 0) + (wv > 1 ? w1 : 0) + (wv > 2 ? w2 : 0);
    int excl = base + scan - n;
    for (int t = 0; t < n; ++t) {
        int slot = excl + t;
        if (slot < MAXM) g_s[slot] = my[t];
    }
    if (l == 0 && tid == 0) cnt[c] = m;
    __syncthreads();
    if (m == 0) {
        if (l == 7 && tid == 0) insub[c] = 0ull;
        return;
    }

    const float* X = feats + (size_t)l * NB * ND;

    // ---- per-thread staging slots + row pointers; prefetch chunk 0 ----
    int nst = 0; short st_i[MAXST], st_k4[MAXST];
    const float* rowp[MAXST];
    for (int idx = tid; idx < (m << 5); idx += NTH) {
        st_i[nst] = (short)(idx >> 5);
        st_k4[nst] = (short)(idx & 31);
        rowp[nst] = X + ((size_t)g_s[idx >> 5] << 9) + ((idx & 31) << 2);
        ++nst;
    }
    float4 pre[MAXST];
    for (int s = 0; s < nst; ++s) pre[s] = *(const float4*)(rowp[s]);

    // ---- triangular slot decode (overlaps chunk-0 load latency) ----
    const int P = m * (m + 1) / 2;    // triangular incl. diag
    float acc0[MAXSLOT], acc1[MAXSLOT];
    short is_[MAXSLOT], js_[MAXSLOT];
    int ns = 0;
    for (int p = tid; p < P; p += NTH) {
        int i = (int)((sqrtf(8.0f * (float)p + 1.0f) - 1.0f) * 0.5f);
        while (((i + 1) * (i + 2)) / 2 <= p) ++i;
        while ((i * (i + 1)) / 2 > p) --i;
        is_[ns] = (short)i;
        js_[ns] = (short)(p - (i * (i + 1)) / 2);
        acc0[ns] = 0.0f; acc1[ns] = 0.0f;
        ++ns;
    }

    // ---- pipelined K-loop: write staged regs, prefetch next, compute ----
    for (int kc = 0; kc < ND; kc += 128) {
        if (kc) __syncthreads();      // previous chunk's readers done
        for (int s = 0; s < nst; ++s)
            *(float4*)&Xt[st_i[s]][st_k4[s] << 2] = pre[s];
        __syncthreads();
        if (kc + 128 < ND)
            for (int s = 0; s < nst; ++s)
                pre[s] = *(const float4*)(rowp[s] + kc + 128);
        for (int s = 0; s < ns; ++s) {
            int i = is_[s], j = js_[s];
            float a0 = acc0[s], a1 = acc1[s];
            #pragma unroll
            for (int k4 = 0; k4 < 32; ++k4) {
                float4 a = *(const float4*)&Xt[i][k4 << 2];
                float4 b = *(const float4*)&Xt[j][k4 << 2];
                a0 = fmaf(a.x, b.x, a0); a1 = fmaf(a.y, b.y, a1);
                a0 = fmaf(a.z, b.z, a0); a1 = fmaf(a.w, b.w, a1);
            }
            acc0[s] = a0; acc1[s] = a1;
        }
    }
    float* Gc = G + ((size_t)l * NLAB + c) * GSTRIDE;
    for (int s = 0; s < ns; ++s) {
        int i = is_[s], j = js_[s];
        float v = acc0[s] + acc1[s];
        Gc[i * MAXM + j] = v;
        Gc[j * MAXM + i] = v;
    }
    if (l != 7) return;

    // ---------- fused phase-1 (layer-7 blocks only) ----------
    float (*Gs)[65] = (float(*)[65])(&Xt[0][0]);   // reuse Xt LDS as raw tile
    __syncthreads();                  // all Xt readers done before overwrite
    for (int s = 0; s < ns; ++s) {
        int i = is_[s], j = js_[s];
        float v = acc0[s] + acc1[s];  // same float as stored to Gc
        Gs[i][j] = v; Gs[j][i] = v;
    }
    if (tid < m) for (int j = m; j < 64; ++j) Gs[tid][j] = -2.0f;  // sentinel cols
    __syncthreads();
    if (tid < 64) {
        rinvp[tid] = (tid < m) ? 1.0f / fmaxf(sqrtf(Gs[tid][tid]), 1e-8f) : 0.0f;
        keep_s[tid] = 0; tops_s[tid] = 0ull;
    }
    __syncthreads();
    unsigned long long tops = 0ull; bool keep = false;
    if (tid < m) {
        float ri = rinvp[tid];
        float v0=-1.f,v1=-1.f,v2=-1.f,v3=-1.f,v4=-1.f;
        int i0=0,i1=0,i2=0,i3=0,i4=0, cand=0;
        #pragma unroll 8
        for (int j = 0; j < 64; ++j) {
            float raw = Gs[tid][j];
            // sentinel (-2) stays negative after scaling; real entries match
            // load_tile's clip(raw*ri*rj) exactly (same op order).
            float v = fminf(fmaxf(raw * ri * rinvp[j], -1.0f), 1.0f);
            if (raw == -2.0f) v = -2.0f;
            if (v > 0.0f && j != tid) {
                ++cand;
                if      (v > v0) { v4=v3;i4=i3; v3=v2;i3=i2; v2=v1;i2=i1; v1=v0;i1=i0; v0=v;i0=j; }
                else if (v > v1) { v4=v3;i4=i3; v3=v2;i3=i2; v2=v1;i2=i1; v1=v;i1=j; }
                else if (v > v2) { v4=v3;i4=i3; v3=v2;i3=i2; v2=v;i2=j; }
                else if (v > v3) { v4=v3;i4=i3; v3=v;i3=j; }
                else if (v > v4) { v4=v;i4=j; }
            }
        }
        keep = (cand >= TOPK_);
        if (keep) tops = (1ull<<i0)|(1ull<<i1)|(1ull<<i2)|(1ull<<i3)|(1ull<<i4);
        keep_s[tid] = keep ? 1 : 0; tops_s[tid] = tops;
    }
    __syncthreads();
    unsigned long long Mrow = 0ull;
    if (tid < m && keep) {
        for (int j = 0; j < 64; ++j) {
            if (j == tid || !keep_s[j]) continue;
            if (((tops >> j) & 1ull) || ((tops_s[j] >> tid) & 1ull)) Mrow |= (1ull << j);
        }
    }
    if (tid < 64) {
        unsigned long long b = __ballot(Mrow != 0ull);
        if (tid == 0) insub[c] = b;
    }
}

// Load normalized+clipped tile: only the m live rows (consumers never read
// rows >= m: every scan guards tid < m). Cols >= m get sentinel -2.0f.
__device__ __forceinline__ void load_tile(
    const float* __restrict__ Gc, int m, int tid, float (*Gs)[65], float* rinv)
{
    if (tid < 64) rinv[tid] = (tid < m) ? 1.0f / fmaxf(sqrtf(Gc[tid * MAXM + tid]), 1e-8f) : 0.0f;
    __syncthreads();
    int tot = m << 4;                  // m rows x 16 float4
    for (int idx4 = tid; idx4 < tot; idx4 += NTH) {
        int i = idx4 >> 4, j0 = (idx4 & 15) << 2;
        float4 raw = *(const float4*)(Gc + i * MAXM + j0);   // poison beyond col m: sentineled
        float ri = rinv[i];
        Gs[i][j0 + 0] = (j0 + 0 < m) ? fminf(fmaxf(raw.x * ri * rinv[j0 + 0], -1.0f), 1.0f) : -2.0f;
        Gs[i][j0 + 1] = (j0 + 1 < m) ? fminf(fmaxf(raw.y * ri * rinv[j0 + 1], -1.0f), 1.0f) : -2.0f;
        Gs[i][j0 + 2] = (j0 + 2 < m) ? fminf(fmaxf(raw.z * ri * rinv[j0 + 2], -1.0f), 1.0f) : -2.0f;
        Gs[i][j0 + 3] = (j0 + 3 < m) ? fminf(fmaxf(raw.w * ri * rinv[j0 + 3], -1.0f), 1.0f) : -2.0f;
    }
    __syncthreads();
}

// ---------------------------------------------------------------------------
// Per (label, layer): subset-restricted knn -> Mbits + ema (insertion top-k).
// ---------------------------------------------------------------------------
__global__ __launch_bounds__(NTH) void k_decide(
    const float* __restrict__ G, const int* __restrict__ cnt,
    const unsigned long long* __restrict__ insub,
    unsigned long long* __restrict__ Mbits, float* __restrict__ ema)
{
    __shared__ float Gs[64][65];
    __shared__ float rinv[64];
    __shared__ unsigned long long tops_s[64];
    __shared__ unsigned char keep_s[64];
    int c = blockIdx.x, l = blockIdx.y, tid = threadIdx.x;
    int m = cnt[c]; if (m > MAXM) m = MAXM;
    if (m == 0) return;
    unsigned long long sub = insub[c];

    const float* Gc = G + ((size_t)l * NLAB + c) * GSTRIDE;
    load_tile(Gc, m, tid, Gs, rinv);
    if (tid < 64) { keep_s[tid] = 0; tops_s[tid] = 0ull; }
    __syncthreads();
    unsigned long long tops = 0ull; bool keep = false; bool act = false;
    float emaval = 0.0f;
    if (tid < m) {
        act = (sub >> tid) & 1ull;
        if (act) {
            float v0=-1.f,v1=-1.f,v2=-1.f,v3=-1.f,v4=-1.f;
            int i0=0,i1=0,i2=0,i3=0,i4=0, cand=0, dg=0;
            float rs = 0.0f;
            #pragma unroll 8
            for (int j = 0; j < 64; ++j) {
                float v = Gs[tid][j];
                if (!((sub >> j) & 1ull)) v = -2.0f;
                if (v > 0.0f) {
                    rs += v; ++dg;                  // includes j == tid (diag ~ 1.0)
                    if (j != tid) {
                        ++cand;
                        if      (v > v0) { v4=v3;i4=i3; v3=v2;i3=i2; v2=v1;i2=i1; v1=v0;i1=i0; v0=v;i0=j; }
                        else if (v > v1) { v4=v3;i4=i3; v3=v2;i3=i2; v2=v1;i2=i1; v1=v;i1=j; }
                        else if (v > v2) { v4=v3;i4=i3; v3=v2;i3=i2; v2=v;i2=j; }
                        else if (v > v3) { v4=v3;i4=i3; v3=v;i3=j; }
                        else if (v > v4) { v4=v;i4=j; }
                    }
                }
            }
            keep = (cand >= TOPK_);
            if (keep) tops = (1ull<<i0)|(1ull<<i1)|(1ull<<i2)|(1ull<<i3)|(1ull<<i4);
            float deg = (float)(dg > 0 ? dg : 1);
            float score = 1.0f / (1.0f + expf(-rs / deg));
            emaval = 0.45f + 0.1f * score;          // MOM*0.5 + (1-MOM)*score
        }
        keep_s[tid] = keep ? 1 : 0; tops_s[tid] = tops;
    }
    __syncthreads();
    if (tid < m) {
        unsigned long long Mrow = 0ull;
        if (keep) {
            for (int j = 0; j < 64; ++j) {
                if (j == tid || !keep_s[j]) continue;
                if (((tops >> j) & 1ull) || ((tops_s[j] >> tid) & 1ull)) Mrow |= (1ull << j);
            }
        }
        Mbits[((size_t)l * NLAB + c) * MAXM + tid] = Mrow;
        ema[((size_t)l * NLAB + c) * MAXM + tid] = emaval;
    }
}

// ---------------------------------------------------------------------------
// Per (label, pair p): masked reduce -> private partial slot. No atomics,
// no fences (round-5 post-mortem: threadfence+ticket cost 63us in L2 thrash).
// ---------------------------------------------------------------------------
__global__ __launch_bounds__(NTH) void k_pairs(
    const float* __restrict__ G, const int* __restrict__ cnt,
    const unsigned long long* __restrict__ Mbits, const float* __restrict__ ema,
    float* __restrict__ partial)   // [NL-1][NLAB][4]
{
    __shared__ float r0[64], r1[64];
    __shared__ unsigned long long M0s[64], M1s[64];
    __shared__ float es[64];
    __shared__ float red[12];      // 4 waves x 3
    int c = blockIdx.x, p = blockIdx.y, tid = threadIdx.x;
    int m = cnt[c]; if (m > MAXM) m = MAXM;
    const float* G0 = G + ((size_t)p       * NLAB + c) * GSTRIDE;
    const float* G1 = G + ((size_t)(p + 1) * NLAB + c) * GSTRIDE;
    if (tid < m) {
        M0s[tid] = Mbits[((size_t)p * NLAB + c) * MAXM + tid];
        M1s[tid] = Mbits[((size_t)(p + 1) * NLAB + c) * MAXM + tid];
        es[tid]  = ema[((size_t)p * NLAB + c) * MAXM + tid];   // W from shallow layer p
        r0[tid]  = 1.0f / fmaxf(sqrtf(G0[tid * MAXM + tid]), 1e-8f);
        r1[tid]  = 1.0f / fmaxf(sqrtf(G1[tid * MAXM + tid]), 1e-8f);
    }
    __syncthreads();
    float fn = 0.0f, fd = 0.0f, fc = 0.0f;
    for (int idx = tid; idx < (m << 6); idx += NTH) {
        int i = idx >> 6, j = idx & 63;
        if (j >= m) continue;
        bool b0 = (M0s[i] >> j) & 1ull;
        bool b1 = (M1s[i] >> j) & 1ull;
        if (b0 | b1) {
            float v0 = b0 ? fminf(fmaxf(G0[idx] * r0[i] * r0[j], -1.0f), 1.0f) : 0.0f;
            float v1 = b1 ? fminf(fmaxf(G1[idx] * r1[i] * r1[j], -1.0f), 1.0f) : 0.0f;
            float w = es[i] * es[j];
            float d = v1 - v0;
            fn = fmaf(d * d, w, fn);
            fd += w;
            fc += 1.0f;
        }
    }
    for (int off = 32; off > 0; off >>= 1) {
        fn += __shfl_down(fn, off);
        fd += __shfl_down(fd, off);
        fc += __shfl_down(fc, off);
    }
    int w = tid >> 6;
    if ((tid & 63) == 0) { red[w * 3] = fn; red[w * 3 + 1] = fd; red[w * 3 + 2] = fc; }
    __syncthreads();
    if (tid == 0) {
        float* dst = partial + ((size_t)p * NLAB + c) * 4;
        dst[0] = red[0] + red[3] + red[6] + red[9];
        dst[1] = red[1] + red[4] + red[7] + red[10];
        dst[2] = red[2] + red[5] + red[8] + red[11];
    }
}

// Single-wave final reduction over 896 private slots (~14 KB, L2-hit).
__global__ void k_final(const float* __restrict__ partial, float* __restrict__ out)
{
    int tid = threadIdx.x;
    float total = 0.0f;
    for (int p = 0; p < NL - 1; ++p) {
        float n = 0.0f, d = 0.0f, cc = 0.0f;
        for (int c = tid; c < NLAB; c += 64) {
            const float* src = partial + ((size_t)p * NLAB + c) * 4;
            n += src[0]; d += src[1]; cc += src[2];
        }
        for (int off = 32; off > 0; off >>= 1) {
            n += __shfl_down(n, off);
            d += __shfl_down(d, off);
            cc += __shfl_down(cc, off);
        }
        if (tid == 0 && cc > 0.0f) total += n / fmaxf(d, 1e-8f);
    }
    if (tid == 0) out[0] = 16.0f * total / 7.0f;   // LAMBDA_ALIGN_K * sum / (L-1)
}

extern "C" void kernel_launch(void* const* d_in, const int* in_sizes, int n_in,
                              void* d_out, int out_size, void* d_ws, size_t ws_size,
                              hipStream_t stream) {
    const float* feats  = (const float*)d_in[0];
    const int*   labels = (const int*)d_in[1];
    // (sample_ids unused by the reference)
    char* w = (char*)d_ws;
    size_t gbytes = (size_t)NL * NLAB * GSTRIDE * 4;                 // 16,777,216
    float*    G       = (float*)(w);
    float*    partial = (float*)(w + gbytes);                        // 14,336 B
    int*      cnt     = (int*)(w + gbytes + 14336);                  // 512 B
    unsigned long long* insub = (unsigned long long*)(w + gbytes + 14848);   // 1,024 B
    unsigned long long* Mbits = (unsigned long long*)(w + gbytes + 16384);   // 524,288
    float*    ema     = (float*)(w + gbytes + 16384 + 524288);       // 262,144
    float*    out     = (float*)d_out;

    k_gram  <<<dim3(NLAB, NL), NTH, 0, stream>>>(feats, labels, G, cnt, insub);
    k_decide<<<dim3(NLAB, NL), NTH, 0, stream>>>(G, cnt, insub, Mbits, ema);
    k_pairs <<<dim3(NLAB, NL - 1), NTH, 0, stream>>>(G, cnt, Mbits, ema, partial);
    k_final <<<1, 64, 0, stream>>>(partial, out);
}

// Round 12
// 130.656 us; speedup vs baseline: 1.0869x; 1.0869x over previous
//
#include <hip/hip_runtime.h>
#include <cmath>

#define NB   2048
#define ND   512
#define NL   8
#define NLAB 128
#define MAXM 64
#define TOPK_ 5
#define NTH  256
#define MAXSLOT 9            // ceil(64*65/2 / 256)
#define GSTRIDE (MAXM*MAXM)  // 4096 floats per (label,layer) gram

// ---------------------------------------------------------------------------
// Fused bucket + raw Gram per (label, layer). Register software pipeline with
// SCALAR slot variables (round-11 post-mortem: dynamically-indexed arrays
// spilled to scratch -> L2 pollution -> 50us). Layer-7 blocks also run
// phase-1 (full-group knn -> insub) from their in-LDS tile.
// ---------------------------------------------------------------------------
#define SLOT_DECL(s) int off##s = -1; int lds##s = 0; float4 pre##s;
#define SLOT_INIT(s) { int idx = tid + (s)*NTH; if (idx < (m << 5)) { \
    int i = idx >> 5, k4 = idx & 31; \
    off##s = (g_s[i] << 9) + (k4 << 2); \
    lds##s = i * 132 + (k4 << 2); \
    pre##s = *(const float4*)(X + off##s); } }
#define SLOT_STORE(s) if (off##s >= 0) *(float4*)(XtF + lds##s) = pre##s;
#define SLOT_FETCH(s, kcn) if (off##s >= 0) pre##s = *(const float4*)(X + off##s + (kcn));

__global__ __launch_bounds__(NTH) void k_gram(
    const float* __restrict__ feats, const int* __restrict__ labels,
    float* __restrict__ G, int* __restrict__ cnt,
    unsigned long long* __restrict__ insub)
{
    __shared__ int wsum[4];
    __shared__ int g_s[MAXM];
    __shared__ float Xt[MAXM][132];   // 132%4==0 -> aligned float4 rows; reused as 64x65 tile
    __shared__ float rinvp[64];
    __shared__ unsigned long long tops_s[64];
    __shared__ unsigned char keep_s[64];
    float* XtF = &Xt[0][0];
    int c = blockIdx.x, l = blockIdx.y, tid = threadIdx.x;
    int lane = tid & 63, wv = tid >> 6;

    // ---- bucket via wave scan (deterministic, index-ascending) ----
    int my[8]; int n = 0; int base_i = tid * 8;
    for (int t = 0; t < 8; ++t) {
        int i = base_i + t;
        if (labels[i] == c) my[n++] = i;
    }
    int scan = n;
    #pragma unroll
    for (int off = 1; off < 64; off <<= 1) {
        int v = __shfl_up(scan, off);
        if (lane >= off) scan += v;
    }
    if (lane == 63) wsum[wv] = scan;
    __syncthreads();
    int w0 = wsum[0], w1 = wsum[1], w2 = wsum[2], w3 = wsum[3];
    int m = w0 + w1 + w2 + w3; if (m > MAXM) m = MAXM;
    int base = (wv > 0 ? w0 : 0) + (wv > 1 ? w1 : 0) + (wv > 2 ? w2 : 0);
    int excl = base + scan - n;
    for (int t = 0; t < n; ++t) {
        int slot = excl + t;
        if (slot < MAXM) g_s[slot] = my[t];
    }
    if (l == 0 && tid == 0) cnt[c] = m;
    __syncthreads();
    if (m == 0) {
        if (l == 7 && tid == 0) insub[c] = 0ull;
        return;
    }

    const float* X = feats + (size_t)l * NB * ND;

    // ---- scalar staging slots; prefetch chunk 0 ----
    SLOT_DECL(0) SLOT_DECL(1) SLOT_DECL(2) SLOT_DECL(3)
    SLOT_DECL(4) SLOT_DECL(5) SLOT_DECL(6) SLOT_DECL(7)
    SLOT_INIT(0) SLOT_INIT(1) SLOT_INIT(2) SLOT_INIT(3)
    SLOT_INIT(4) SLOT_INIT(5) SLOT_INIT(6) SLOT_INIT(7)

    // ---- triangular slot decode (overlaps chunk-0 load latency) ----
    const int P = m * (m + 1) / 2;    // triangular incl. diag
    float acc0[MAXSLOT], acc1[MAXSLOT];
    short is_[MAXSLOT], js_[MAXSLOT];
    int ns = 0;
    for (int p = tid; p < P; p += NTH) {
        int i = (int)((sqrtf(8.0f * (float)p + 1.0f) - 1.0f) * 0.5f);
        while (((i + 1) * (i + 2)) / 2 <= p) ++i;
        while ((i * (i + 1)) / 2 > p) --i;
        is_[ns] = (short)i;
        js_[ns] = (short)(p - (i * (i + 1)) / 2);
        acc0[ns] = 0.0f; acc1[ns] = 0.0f;
        ++ns;
    }

    // ---- pipelined K-loop: store staged regs, prefetch next, compute ----
    for (int kc = 0; kc < ND; kc += 128) {
        if (kc) __syncthreads();      // previous chunk's readers done
        SLOT_STORE(0) SLOT_STORE(1) SLOT_STORE(2) SLOT_STORE(3)
        SLOT_STORE(4) SLOT_STORE(5) SLOT_STORE(6) SLOT_STORE(7)
        __syncthreads();
        if (kc + 128 < ND) {
            int kcn = kc + 128;
            SLOT_FETCH(0, kcn) SLOT_FETCH(1, kcn) SLOT_FETCH(2, kcn) SLOT_FETCH(3, kcn)
            SLOT_FETCH(4, kcn) SLOT_FETCH(5, kcn) SLOT_FETCH(6, kcn) SLOT_FETCH(7, kcn)
        }
        for (int s = 0; s < ns; ++s) {
            int i = is_[s], j = js_[s];
            float a0 = acc0[s], a1 = acc1[s];
            #pragma unroll
            for (int k4 = 0; k4 < 32; ++k4) {
                float4 a = *(const float4*)&Xt[i][k4 << 2];
                float4 b = *(const float4*)&Xt[j][k4 << 2];
                a0 = fmaf(a.x, b.x, a0); a1 = fmaf(a.y, b.y, a1);
                a0 = fmaf(a.z, b.z, a0); a1 = fmaf(a.w, b.w, a1);
            }
            acc0[s] = a0; acc1[s] = a1;
        }
    }
    float* Gc = G + ((size_t)l * NLAB + c) * GSTRIDE;
    for (int s = 0; s < ns; ++s) {
        int i = is_[s], j = js_[s];
        float v = acc0[s] + acc1[s];
        Gc[i * MAXM + j] = v;
        Gc[j * MAXM + i] = v;
    }
    if (l != 7) return;

    // ---------- fused phase-1 (layer-7 blocks only) ----------
    float (*Gs)[65] = (float(*)[65])(&Xt[0][0]);   // reuse Xt LDS as raw tile
    __syncthreads();                  // all Xt readers done before overwrite
    for (int s = 0; s < ns; ++s) {
        int i = is_[s], j = js_[s];
        float v = acc0[s] + acc1[s];  // same float as stored to Gc
        Gs[i][j] = v; Gs[j][i] = v;
    }
    if (tid < m) for (int j = m; j < 64; ++j) Gs[tid][j] = -2.0f;  // sentinel cols
    __syncthreads();
    if (tid < 64) {
        rinvp[tid] = (tid < m) ? 1.0f / fmaxf(sqrtf(Gs[tid][tid]), 1e-8f) : 0.0f;
        keep_s[tid] = 0; tops_s[tid] = 0ull;
    }
    __syncthreads();
    unsigned long long tops = 0ull; bool keep = false;
    if (tid < m) {
        float ri = rinvp[tid];
        float v0=-1.f,v1=-1.f,v2=-1.f,v3=-1.f,v4=-1.f;
        int i0=0,i1=0,i2=0,i3=0,i4=0, cand=0;
        #pragma unroll 8
        for (int j = 0; j < 64; ++j) {
            float raw = Gs[tid][j];
            // sentinel (-2) stays negative after scaling; real entries match
            // load_tile's clip(raw*ri*rj) exactly (same op order).
            float v = fminf(fmaxf(raw * ri * rinvp[j], -1.0f), 1.0f);
            if (raw == -2.0f) v = -2.0f;
            if (v > 0.0f && j != tid) {
                ++cand;
                if      (v > v0) { v4=v3;i4=i3; v3=v2;i3=i2; v2=v1;i2=i1; v1=v0;i1=i0; v0=v;i0=j; }
                else if (v > v1) { v4=v3;i4=i3; v3=v2;i3=i2; v2=v1;i2=i1; v1=v;i1=j; }
                else if (v > v2) { v4=v3;i4=i3; v3=v2;i3=i2; v2=v;i2=j; }
                else if (v > v3) { v4=v3;i4=i3; v3=v;i3=j; }
                else if (v > v4) { v4=v;i4=j; }
            }
        }
        keep = (cand >= TOPK_);
        if (keep) tops = (1ull<<i0)|(1ull<<i1)|(1ull<<i2)|(1ull<<i3)|(1ull<<i4);
        keep_s[tid] = keep ? 1 : 0; tops_s[tid] = tops;
    }
    __syncthreads();
    unsigned long long Mrow = 0ull;
    if (tid < m && keep) {
        for (int j = 0; j < 64; ++j) {
            if (j == tid || !keep_s[j]) continue;
            if (((tops >> j) & 1ull) || ((tops_s[j] >> tid) & 1ull)) Mrow |= (1ull << j);
        }
    }
    if (tid < 64) {
        unsigned long long b = __ballot(Mrow != 0ull);
        if (tid == 0) insub[c] = b;
    }
}

// Load normalized+clipped tile: only the m live rows (consumers never read
// rows >= m: every scan guards tid < m). Cols >= m get sentinel -2.0f.
__device__ __forceinline__ void load_tile(
    const float* __restrict__ Gc, int m, int tid, float (*Gs)[65], float* rinv)
{
    if (tid < 64) rinv[tid] = (tid < m) ? 1.0f / fmaxf(sqrtf(Gc[tid * MAXM + tid]), 1e-8f) : 0.0f;
    __syncthreads();
    int tot = m << 4;                  // m rows x 16 float4
    for (int idx4 = tid; idx4 < tot; idx4 += NTH) {
        int i = idx4 >> 4, j0 = (idx4 & 15) << 2;
        float4 raw = *(const float4*)(Gc + i * MAXM + j0);   // poison beyond col m: sentineled
        float ri = rinv[i];
        Gs[i][j0 + 0] = (j0 + 0 < m) ? fminf(fmaxf(raw.x * ri * rinv[j0 + 0], -1.0f), 1.0f) : -2.0f;
        Gs[i][j0 + 1] = (j0 + 1 < m) ? fminf(fmaxf(raw.y * ri * rinv[j0 + 1], -1.0f), 1.0f) : -2.0f;
        Gs[i][j0 + 2] = (j0 + 2 < m) ? fminf(fmaxf(raw.z * ri * rinv[j0 + 2], -1.0f), 1.0f) : -2.0f;
        Gs[i][j0 + 3] = (j0 + 3 < m) ? fminf(fmaxf(raw.w * ri * rinv[j0 + 3], -1.0f), 1.0f) : -2.0f;
    }
    __syncthreads();
}

// ---------------------------------------------------------------------------
// Per (label, layer): subset-restricted knn -> Mbits + ema (insertion top-k).
// ---------------------------------------------------------------------------
__global__ __launch_bounds__(NTH) void k_decide(
    const float* __restrict__ G, const int* __restrict__ cnt,
    const unsigned long long* __restrict__ insub,
    unsigned long long* __restrict__ Mbits, float* __restrict__ ema)
{
    __shared__ float Gs[64][65];
    __shared__ float rinv[64];
    __shared__ unsigned long long tops_s[64];
    __shared__ unsigned char keep_s[64];
    int c = blockIdx.x, l = blockIdx.y, tid = threadIdx.x;
    int m = cnt[c]; if (m > MAXM) m = MAXM;
    if (m == 0) return;
    unsigned long long sub = insub[c];

    const float* Gc = G + ((size_t)l * NLAB + c) * GSTRIDE;
    load_tile(Gc, m, tid, Gs, rinv);
    if (tid < 64) { keep_s[tid] = 0; tops_s[tid] = 0ull; }
    __syncthreads();
    unsigned long long tops = 0ull; bool keep = false; bool act = false;
    float emaval = 0.0f;
    if (tid < m) {
        act = (sub >> tid) & 1ull;
        if (act) {
            float v0=-1.f,v1=-1.f,v2=-1.f,v3=-1.f,v4=-1.f;
            int i0=0,i1=0,i2=0,i3=0,i4=0, cand=0, dg=0;
            float rs = 0.0f;
            #pragma unroll 8
            for (int j = 0; j < 64; ++j) {
                float v = Gs[tid][j];
                if (!((sub >> j) & 1ull)) v = -2.0f;
                if (v > 0.0f) {
                    rs += v; ++dg;                  // includes j == tid (diag ~ 1.0)
                    if (j != tid) {
                        ++cand;
                        if      (v > v0) { v4=v3;i4=i3; v3=v2;i3=i2; v2=v1;i2=i1; v1=v0;i1=i0; v0=v;i0=j; }
                        else if (v > v1) { v4=v3;i4=i3; v3=v2;i3=i2; v2=v1;i2=i1; v1=v;i1=j; }
                        else if (v > v2) { v4=v3;i4=i3; v3=v2;i3=i2; v2=v;i2=j; }
                        else if (v > v3) { v4=v3;i4=i3; v3=v;i3=j; }
                        else if (v > v4) { v4=v;i4=j; }
                    }
                }
            }
            keep = (cand >= TOPK_);
            if (keep) tops = (1ull<<i0)|(1ull<<i1)|(1ull<<i2)|(1ull<<i3)|(1ull<<i4);
            float deg = (float)(dg > 0 ? dg : 1);
            float score = 1.0f / (1.0f + expf(-rs / deg));
            emaval = 0.45f + 0.1f * score;          // MOM*0.5 + (1-MOM)*score
        }
        keep_s[tid] = keep ? 1 : 0; tops_s[tid] = tops;
    }
    __syncthreads();
    if (tid < m) {
        unsigned long long Mrow = 0ull;
        if (keep) {
            for (int j = 0; j < 64; ++j) {
                if (j == tid || !keep_s[j]) continue;
                if (((tops >> j) & 1ull) || ((tops_s[j] >> tid) & 1ull)) Mrow |= (1ull << j);
            }
        }
        Mbits[((size_t)l * NLAB + c) * MAXM + tid] = Mrow;
        ema[((size_t)l * NLAB + c) * MAXM + tid] = emaval;
    }
}

// ---------------------------------------------------------------------------
// Per (label, pair p): masked reduce -> private partial slot. No atomics,
// no fences (round-5 post-mortem: threadfence+ticket cost 63us in L2 thrash).
// ---------------------------------------------------------------------------
__global__ __launch_bounds__(NTH) void k_pairs(
    const float* __restrict__ G, const int* __restrict__ cnt,
    const unsigned long long* __restrict__ Mbits, const float* __restrict__ ema,
    float* __restrict__ partial)   // [NL-1][NLAB][4]
{
    __shared__ float r0[64], r1[64];
    __shared__ unsigned long long M0s[64], M1s[64];
    __shared__ float es[64];
    __shared__ float red[12];      // 4 waves x 3
    int c = blockIdx.x, p = blockIdx.y, tid = threadIdx.x;
    int m = cnt[c]; if (m > MAXM) m = MAXM;
    const float* G0 = G + ((size_t)p       * NLAB + c) * GSTRIDE;
    const float* G1 = G + ((size_t)(p + 1) * NLAB + c) * GSTRIDE;
    if (tid < m) {
        M0s[tid] = Mbits[((size_t)p * NLAB + c) * MAXM + tid];
        M1s[tid] = Mbits[((size_t)(p + 1) * NLAB + c) * MAXM + tid];
        es[tid]  = ema[((size_t)p * NLAB + c) * MAXM + tid];   // W from shallow layer p
        r0[tid]  = 1.0f / fmaxf(sqrtf(G0[tid * MAXM + tid]), 1e-8f);
        r1[tid]  = 1.0f / fmaxf(sqrtf(G1[tid * MAXM + tid]), 1e-8f);
    }
    __syncthreads();
    float fn = 0.0f, fd = 0.0f, fc = 0.0f;
    for (int idx = tid; idx < (m << 6); idx += NTH) {
        int i = idx >> 6, j = idx & 63;
        if (j >= m) continue;
        bool b0 = (M0s[i] >> j) & 1ull;
        bool b1 = (M1s[i] >> j) & 1ull;
        if (b0 | b1) {
            float v0 = b0 ? fminf(fmaxf(G0[idx] * r0[i] * r0[j], -1.0f), 1.0f) : 0.0f;
            float v1 = b1 ? fminf(fmaxf(G1[idx] * r1[i] * r1[j], -1.0f), 1.0f) : 0.0f;
            float w = es[i] * es[j];
            float d = v1 - v0;
            fn = fmaf(d * d, w, fn);
            fd += w;
            fc += 1.0f;
        }
    }
    for (int off = 32; off > 0; off >>= 1) {
        fn += __shfl_down(fn, off);
        fd += __shfl_down(fd, off);
        fc += __shfl_down(fc, off);
    }
    int w = tid >> 6;
    if ((tid & 63) == 0) { red[w * 3] = fn; red[w * 3 + 1] = fd; red[w * 3 + 2] = fc; }
    __syncthreads();
    if (tid == 0) {
        float* dst = partial + ((size_t)p * NLAB + c) * 4;
        dst[0] = red[0] + red[3] + red[6] + red[9];
        dst[1] = red[1] + red[4] + red[7] + red[10];
        dst[2] = red[2] + red[5] + red[8] + red[11];
    }
}

// Single-wave final reduction over 896 private slots (~14 KB, L2-hit).
__global__ void k_final(const float* __restrict__ partial, float* __restrict__ out)
{
    int tid = threadIdx.x;
    float total = 0.0f;
    for (int p = 0; p < NL - 1; ++p) {
        float n = 0.0f, d = 0.0f, cc = 0.0f;
        for (int c = tid; c < NLAB; c += 64) {
            const float* src = partial + ((size_t)p * NLAB + c) * 4;
            n += src[0]; d += src[1]; cc += src[2];
        }
        for (int off = 32; off > 0; off >>= 1) {
            n += __shfl_down(n, off);
            d += __shfl_down(d, off);
            cc += __shfl_down(cc, off);
        }
        if (tid == 0 && cc > 0.0f) total += n / fmaxf(d, 1e-8f);
    }
    if (tid == 0) out[0] = 16.0f * total / 7.0f;   // LAMBDA_ALIGN_K * sum / (L-1)
}

extern "C" void kernel_launch(void* const* d_in, const int* in_sizes, int n_in,
                              void* d_out, int out_size, void* d_ws, size_t ws_size,
                              hipStream_t stream) {
    const float* feats  = (const float*)d_in[0];
    const int*   labels = (const int*)d_in[1];
    // (sample_ids unused by the reference)
    char* w = (char*)d_ws;
    size_t gbytes = (size_t)NL * NLAB * GSTRIDE * 4;                 // 16,777,216
    float*    G       = (float*)(w);
    float*    partial = (float*)(w + gbytes);                        // 14,336 B
    int*      cnt     = (int*)(w + gbytes + 14336);                  // 512 B
    unsigned long long* insub = (unsigned long long*)(w + gbytes + 14848);   // 1,024 B
    unsigned long long* Mbits = (unsigned long long*)(w + gbytes + 16384);   // 524,288
    float*    ema     = (float*)(w + gbytes + 16384 + 524288);       // 262,144
    float*    out     = (float*)d_out;

    k_gram  <<<dim3(NLAB, NL), NTH, 0, stream>>>(feats, labels, G, cnt, insub);
    k_decide<<<dim3(NLAB, NL), NTH, 0, stream>>>(G, cnt, insub, Mbits, ema);
    k_pairs <<<dim3(NLAB, NL - 1), NTH, 0, stream>>>(G, cnt, Mbits, ema, partial);
    k_final <<<1, 64, 0, stream>>>(partial, out);
}